// Round 13
// baseline (109.169 us; speedup 1.0000x reference)
//
#include <hip/hip_runtime.h>

// Problem constants (from reference): N=16384, M=8192, D_IN=D_OUT=512
#define NN 16384
#define MM 8192
#define DD 512

// MALL-residency split: rows >= NT_SPLIT use REGULAR (cache-allocating)
// stores; rows < NT_SPLIT use nontemporal stores (bypass).
// Measured curve (savings vs all-nt 106.7 us):
//   regular region  0 MB -> 0 MB saved   (R4,  106.7)
//   regular 128 MB -> 35 MB saved        (R12, 101.5)
//   regular 192 MB -> 49 MB saved        (R10,  99.4)
//   regular 537 MB -> negative           (R11, 112.0; full churn)
// Retention fraction ~26% constant -> absolute saving grows with region.
// R13 probe: regular = 8192 rows = 256 MB.
#define NT_SPLIT 8192

// clang-native 4-float vector (HIP's float4 is a class).
typedef float floatx4 __attribute__((ext_vector_type(4)));

// ---------------------------------------------------------------------------
// Kernel 1: v[b] = dot(W{1,2}[b,:], W3)   for b in [0, 1024)
// ---------------------------------------------------------------------------
__global__ void __launch_bounds__(256) gemv_w(const float* __restrict__ W1,
                                              const float* __restrict__ W2,
                                              const float* __restrict__ W3,
                                              float* __restrict__ v) {
    int b = blockIdx.x;
    const float* W = (b < DD) ? W1 : W2;
    int row = (b < DD) ? b : b - DD;
    const float* wr = W + (size_t)row * DD;
    int tid = threadIdx.x;
    float sum = 0.f;
    #pragma unroll
    for (int j = tid; j < DD; j += 256) sum += wr[j] * W3[j];
    #pragma unroll
    for (int off = 32; off > 0; off >>= 1) sum += __shfl_down(sum, off, 64);
    __shared__ float ws[4];
    int lane = tid & 63, w = tid >> 6;
    if (lane == 0) ws[w] = sum;
    __syncthreads();
    if (tid == 0) v[b] = ws[0] + ws[1] + ws[2] + ws[3];
}

// ---------------------------------------------------------------------------
// Kernel 2: one wave per row.
//   row < NN : s[row] = dot(node[row,:], v1)
//   row >= NN: s[row] = dot(sub[row-NN,:], v2) + b3
// ---------------------------------------------------------------------------
__global__ void __launch_bounds__(256) row_dots(const float* __restrict__ node,
                                                const float* __restrict__ sub,
                                                const float* __restrict__ v,
                                                const float* __restrict__ b3,
                                                float* __restrict__ s) {
    int wid = threadIdx.x >> 6;
    int lane = threadIdx.x & 63;
    int row = blockIdx.x * 4 + wid;
    const float* x;
    const float* vv;
    float bias;
    if (row < NN) {
        x = node + (size_t)row * DD;
        vv = v;            // v1
        bias = 0.f;
    } else {
        x = sub + (size_t)(row - NN) * DD;
        vv = v + DD;       // v2
        bias = b3[0];
    }
    const floatx4* x4 = (const floatx4*)x;
    const floatx4* v4 = (const floatx4*)vv;
    floatx4 a0 = x4[lane],      c0 = v4[lane];
    floatx4 a1 = x4[lane + 64], c1 = v4[lane + 64];
    float sum = a0.x * c0.x + a0.y * c0.y + a0.z * c0.z + a0.w * c0.w
              + a1.x * c1.x + a1.y * c1.y + a1.z * c1.z + a1.w * c1.w;
    #pragma unroll
    for (int off = 32; off > 0; off >>= 1) sum += __shfl_down(sum, off, 64);
    if (lane == 0) s[row] = sum + bias;
}

// ---------------------------------------------------------------------------
// Kernel 3: out[i][j] = s1[i] + s2[j].  Column-stationary with partitioned
// store policy:
//   rows <  NT_SPLIT : nontemporal stores (bypass, no MALL churn)
//   rows >= NT_SPLIT : regular stores (MALL-resident across replays)
// grid = (MM/4/256, NN/32) = (8, 512); block = 256.
// ---------------------------------------------------------------------------
__global__ void __launch_bounds__(256) add_outer(const float* __restrict__ s1,
                                                 const float* __restrict__ s2,
                                                 floatx4* __restrict__ out) {
    int j4 = blockIdx.x * 256 + threadIdx.x;   // 0 .. MM/4-1
    int i0 = blockIdx.y * 32;                  // row tile base
    floatx4 b = ((const floatx4*)s2)[j4];      // loaded once, lives in VGPRs
    const float* s1p = s1 + i0;
    floatx4* o = out + (size_t)i0 * (MM / 4) + j4;
    if (i0 >= NT_SPLIT) {
        // resident region: regular stores
        #pragma unroll 4
        for (int k = 0; k < 32; ++k) {
            float a = s1p[k];
            floatx4 vo;
            vo.x = a + b.x; vo.y = a + b.y; vo.z = a + b.z; vo.w = a + b.w;
            o[(size_t)k * (MM / 4)] = vo;
        }
    } else {
        // streaming region: nontemporal stores
        #pragma unroll 4
        for (int k = 0; k < 32; ++k) {
            float a = s1p[k];
            floatx4 vo;
            vo.x = a + b.x; vo.y = a + b.y; vo.z = a + b.z; vo.w = a + b.w;
            __builtin_nontemporal_store(vo, &o[(size_t)k * (MM / 4)]);
        }
    }
}

extern "C" void kernel_launch(void* const* d_in, const int* in_sizes, int n_in,
                              void* d_out, int out_size, void* d_ws, size_t ws_size,
                              hipStream_t stream) {
    const float* node = (const float*)d_in[0];   // [NN, DD]
    const float* sub  = (const float*)d_in[1];   // [MM, DD]
    const float* W1   = (const float*)d_in[2];   // [DD, DD]
    const float* W2   = (const float*)d_in[3];   // [DD, DD]
    const float* W3   = (const float*)d_in[4];   // [DD, 1]
    const float* b3   = (const float*)d_in[5];   // [1]
    float* out = (float*)d_out;                  // [NN, MM]

    float* ws = (float*)d_ws;
    float* v  = ws;          // 1024 floats: v1 (512) then v2 (512)
    float* s  = ws + 1024;   // NN + MM floats: s1 (NN) then s2 (MM)

    // 1) v1 = W1 @ W3, v2 = W2 @ W3
    gemv_w<<<2 * DD, 256, 0, stream>>>(W1, W2, W3, v);

    // 2) s1 = node @ v1 ; s2 = sub @ v2 + b3   (one wave per row)
    row_dots<<<(NN + MM) / 4, 256, 0, stream>>>(node, sub, v, b3, s);

    // 3) out = s1[:,None] + s2[None,:]  (partitioned store policy)
    dim3 grid(MM / 4 / 256, NN / 32);
    add_outer<<<grid, 256, 0, stream>>>(s, s + NN, (floatx4*)out);
}

// Round 14
// 99.565 us; speedup vs baseline: 1.0965x; 1.0965x over previous
//
#include <hip/hip_runtime.h>

// Problem constants (from reference): N=16384, M=8192, D_IN=D_OUT=512
#define NN 16384
#define MM 8192
#define DD 512

// MALL-residency split: rows >= NT_SPLIT use REGULAR (cache-allocating)
// stores; rows < NT_SPLIT use nontemporal stores (bypass).
// Measured savings-vs-all-nt(106.7us) curve over regular-region size:
//   0 MB -> 0          (R4,  106.7)
//   128 MB -> +5.2 us  (R12, 101.5)
//   192 MB -> +7.3 us  (R10,  99.4)  <- optimum (demand 242/256 MB MALL)
//   256 MB -> -2.5 us  (R13, 109.2)  <- churn cliff (demand 304 MB)
//   537 MB -> -5.3 us  (R11, 112.0)  <- full churn + writeback overhead
// Retention fraction ~26% in the fitting regime; collapses past capacity.
#define NT_SPLIT 10240

// clang-native 4-float vector (HIP's float4 is a class).
typedef float floatx4 __attribute__((ext_vector_type(4)));

// ---------------------------------------------------------------------------
// Kernel 1: v[b] = dot(W{1,2}[b,:], W3)   for b in [0, 1024)
// ---------------------------------------------------------------------------
__global__ void __launch_bounds__(256) gemv_w(const float* __restrict__ W1,
                                              const float* __restrict__ W2,
                                              const float* __restrict__ W3,
                                              float* __restrict__ v) {
    int b = blockIdx.x;
    const float* W = (b < DD) ? W1 : W2;
    int row = (b < DD) ? b : b - DD;
    const float* wr = W + (size_t)row * DD;
    int tid = threadIdx.x;
    float sum = 0.f;
    #pragma unroll
    for (int j = tid; j < DD; j += 256) sum += wr[j] * W3[j];
    #pragma unroll
    for (int off = 32; off > 0; off >>= 1) sum += __shfl_down(sum, off, 64);
    __shared__ float ws[4];
    int lane = tid & 63, w = tid >> 6;
    if (lane == 0) ws[w] = sum;
    __syncthreads();
    if (tid == 0) v[b] = ws[0] + ws[1] + ws[2] + ws[3];
}

// ---------------------------------------------------------------------------
// Kernel 2: one wave per row.
//   row < NN : s[row] = dot(node[row,:], v1)
//   row >= NN: s[row] = dot(sub[row-NN,:], v2) + b3
// ---------------------------------------------------------------------------
__global__ void __launch_bounds__(256) row_dots(const float* __restrict__ node,
                                                const float* __restrict__ sub,
                                                const float* __restrict__ v,
                                                const float* __restrict__ b3,
                                                float* __restrict__ s) {
    int wid = threadIdx.x >> 6;
    int lane = threadIdx.x & 63;
    int row = blockIdx.x * 4 + wid;
    const float* x;
    const float* vv;
    float bias;
    if (row < NN) {
        x = node + (size_t)row * DD;
        vv = v;            // v1
        bias = 0.f;
    } else {
        x = sub + (size_t)(row - NN) * DD;
        vv = v + DD;       // v2
        bias = b3[0];
    }
    const floatx4* x4 = (const floatx4*)x;
    const floatx4* v4 = (const floatx4*)vv;
    floatx4 a0 = x4[lane],      c0 = v4[lane];
    floatx4 a1 = x4[lane + 64], c1 = v4[lane + 64];
    float sum = a0.x * c0.x + a0.y * c0.y + a0.z * c0.z + a0.w * c0.w
              + a1.x * c1.x + a1.y * c1.y + a1.z * c1.z + a1.w * c1.w;
    #pragma unroll
    for (int off = 32; off > 0; off >>= 1) sum += __shfl_down(sum, off, 64);
    if (lane == 0) s[row] = sum + bias;
}

// ---------------------------------------------------------------------------
// Kernel 3: out[i][j] = s1[i] + s2[j].  Column-stationary with partitioned
// store policy:
//   rows <  NT_SPLIT : nontemporal stores (bypass, no MALL churn)
//   rows >= NT_SPLIT : regular stores (MALL-resident across replays)
// grid = (MM/4/256, NN/32) = (8, 512); block = 256.
// ---------------------------------------------------------------------------
__global__ void __launch_bounds__(256) add_outer(const float* __restrict__ s1,
                                                 const float* __restrict__ s2,
                                                 floatx4* __restrict__ out) {
    int j4 = blockIdx.x * 256 + threadIdx.x;   // 0 .. MM/4-1
    int i0 = blockIdx.y * 32;                  // row tile base
    floatx4 b = ((const floatx4*)s2)[j4];      // loaded once, lives in VGPRs
    const float* s1p = s1 + i0;
    floatx4* o = out + (size_t)i0 * (MM / 4) + j4;
    if (i0 >= NT_SPLIT) {
        // resident region: regular stores
        #pragma unroll 4
        for (int k = 0; k < 32; ++k) {
            float a = s1p[k];
            floatx4 vo;
            vo.x = a + b.x; vo.y = a + b.y; vo.z = a + b.z; vo.w = a + b.w;
            o[(size_t)k * (MM / 4)] = vo;
        }
    } else {
        // streaming region: nontemporal stores
        #pragma unroll 4
        for (int k = 0; k < 32; ++k) {
            float a = s1p[k];
            floatx4 vo;
            vo.x = a + b.x; vo.y = a + b.y; vo.z = a + b.z; vo.w = a + b.w;
            __builtin_nontemporal_store(vo, &o[(size_t)k * (MM / 4)]);
        }
    }
}

extern "C" void kernel_launch(void* const* d_in, const int* in_sizes, int n_in,
                              void* d_out, int out_size, void* d_ws, size_t ws_size,
                              hipStream_t stream) {
    const float* node = (const float*)d_in[0];   // [NN, DD]
    const float* sub  = (const float*)d_in[1];   // [MM, DD]
    const float* W1   = (const float*)d_in[2];   // [DD, DD]
    const float* W2   = (const float*)d_in[3];   // [DD, DD]
    const float* W3   = (const float*)d_in[4];   // [DD, 1]
    const float* b3   = (const float*)d_in[5];   // [1]
    float* out = (float*)d_out;                  // [NN, MM]

    float* ws = (float*)d_ws;
    float* v  = ws;          // 1024 floats: v1 (512) then v2 (512)
    float* s  = ws + 1024;   // NN + MM floats: s1 (NN) then s2 (MM)

    // 1) v1 = W1 @ W3, v2 = W2 @ W3
    gemv_w<<<2 * DD, 256, 0, stream>>>(W1, W2, W3, v);

    // 2) s1 = node @ v1 ; s2 = sub @ v2 + b3   (one wave per row)
    row_dots<<<(NN + MM) / 4, 256, 0, stream>>>(node, sub, v, b3, s);

    // 3) out = s1[:,None] + s2[None,:]  (partitioned store policy)
    dim3 grid(MM / 4 / 256, NN / 32);
    add_outer<<<grid, 256, 0, stream>>>(s, s + NN, (floatx4*)out);
}